// Round 14
// baseline (284.213 us; speedup 1.0000x reference)
//
#include <hip/hip_runtime.h>
#include <cstddef>

#define DD 128
#define BN_EPS 1e-5f
#define SLOPE 0.01f
#define BSH 6              // 64 dst rows per bucket
#define BROWS 64
#define CAP 4096           // aggemm per-window edge capacity in LDS
#define SCHUNK 8192        // scatb per-block edge chunk
#define CSH 13             // src-chunk shift: 8192 rows = 2 MB bf16, L2-resident
#define NCH 7              // ceil(50000/8192)
#define PREPB 200          // dedicated prep blocks in K1

typedef __attribute__((ext_vector_type(8))) short short8;
typedef __attribute__((ext_vector_type(4))) float float4v;

__device__ __forceinline__ unsigned short f2b(float x) {
    unsigned b = __float_as_uint(x);
    b += 0x7fffu + ((b >> 16) & 1u);   // round-to-nearest-even
    return (unsigned short)(b >> 16);
}
__device__ __forceinline__ float lo16(unsigned x) { return __uint_as_float(x << 16); }
__device__ __forceinline__ float hi16(unsigned x) { return __uint_as_float(x & 0xffff0000u); }

// ---------- K1: role-split — sort blocks [0,NS) + prep blocks [NS,NS+PREPB) ----------
// R13's fused K1 ran 196 blocks (<1/CU, 60 CUs idle) and serialized prep
// before sort. Splitting roles across one grid fills the machine and overlaps.
__global__ __launch_bounds__(1024) void scatb6_kernel(
        const float* __restrict__ h, ushort* __restrict__ hb,
        const float* __restrict__ W1, const float* __restrict__ W2,
        ushort* __restrict__ wt1, ushort* __restrict__ wt2,
        const int* __restrict__ src, const int* __restrict__ dst,
        int* __restrict__ cnt, int* __restrict__ lofs,
        unsigned* __restrict__ packed, float* __restrict__ stats,
        int NS, int total4, int E, int NB) {
    __shared__ int bins[1024];
    __shared__ int lcur[1024];
    __shared__ int wtot[16];
    __shared__ unsigned sbuf[SCHUNK];

    const int t = threadIdx.x;
    const int blk = blockIdx.x;

    if (blk >= NS) {
        // ---- prep role ----
        const int pb = blk - NS;
        const int gid = pb * 1024 + t;
        const int gstride = PREPB * 1024;
        if (pb == 0 && t < 256) stats[t] = 0.f;
        for (int i = gid; i < total4; i += gstride) {
            float4 v = ((const float4*)h)[i];
            ushort4 o;
            o.x = f2b(v.x); o.y = f2b(v.y); o.z = f2b(v.z); o.w = f2b(v.w);
            ((ushort4*)hb)[i] = o;
        }
        for (int i = gid; i < 2 * DD * DD; i += gstride) {
            int wsel = i >> 14;
            int r = i & 16383;
            int c = r >> 7, k = r & 127;
            const float* Wsrc = wsel ? W2 : W1;
            ushort* Wdst = wsel ? wt2 : wt1;
            Wdst[c * DD + k] = f2b(Wsrc[k * DD + c]);
        }
        return;
    }

    // ---- sort role ----
    const int lane = t & 63;
    const int w = t >> 6;
    const int s = blk;
    const int cs = s * SCHUNK;
    const int cn = min(SCHUNK, E - cs);

    bins[t] = 0;
    __syncthreads();
    for (int i = t; i < cn; i += 1024) atomicAdd(&bins[dst[cs + i] >> BSH], 1);
    __syncthreads();
    int v = bins[t];
    int si = v;
#pragma unroll
    for (int d = 1; d < 64; d <<= 1) {
        int u = __shfl_up(si, d);
        if (lane >= d) si += u;
    }
    if (lane == 63) wtot[w] = si;
    __syncthreads();
    if (t == 0) {
        int a = 0;
#pragma unroll
        for (int k = 0; k < 16; ++k) { int x = wtot[k]; wtot[k] = a; a += x; }
    }
    __syncthreads();
    int excl = wtot[w] + si - v;
    lcur[t] = excl;
    if (t < NB) {
        cnt[(size_t)s * NB + t] = v;
        lofs[(size_t)s * NB + t] = excl;
    }
    __syncthreads();
    for (int i = t; i < cn; i += 1024) {
        int d = dst[cs + i];
        int b = d >> BSH;
        int pos = atomicAdd(&lcur[b], 1);
        sbuf[pos] = ((unsigned)(d & (BROWS - 1)) << 16) | (unsigned)src[cs + i];
    }
    __syncthreads();
    for (int i = t; i < cn; i += 1024) packed[cs + i] = sbuf[i];
}

// ---------- K2: fused gather + GEMM1 ----------
// __launch_bounds__(1024, 8): forces 2 blocks/CU (32 waves). This DOES spill
// some accumulator state (~50 MB scratch traffic) but measured A/B (R10/R13
// 93us @63% occ vs R12 124us @34% occ spill-free) shows 2x waves wins for
// this latency-bound gather. Do not "fix" the spill.
// Gather core: batched 4-node walk — per c-chunk a wave advances its 4 node
// segments together: 4 independent uint4 loads in flight (segments are ~4.5
// edges, so the old per-segment loop had trip~1 and no load pipelining);
// predicated accumulate via fmaf(mask,..) costs the same VALU as plain add.
__global__ __launch_bounds__(1024, 8) void aggemm_kernel(
        const ushort* __restrict__ hb, const int* __restrict__ cnt,
        const int* __restrict__ lofs, const unsigned* __restrict__ packed,
        const float* __restrict__ eps_ptr, const ushort* __restrict__ wt,
        const float* __restrict__ bias, ushort* __restrict__ z1b,
        int n, int NB, int NS) {
    __shared__ __align__(16) char smem[52224];
    __shared__ int wtot[16];
    __shared__ int etot;

    int* rcnt  = (int*)smem;                       // 256
    int* rsoff = rcnt + 256;                       // 256
    int* rpre  = rsoff + 256;                      // 256
    int* bins  = rpre + 256;                       // 512
    int* cofs  = bins + 512;                       // 513
    int* ccur  = cofs + 513;                       // 512
    unsigned* sbufA = (unsigned*)(smem + 9728);    // 16384 B
    ushort*  sbufB  = (ushort*)(smem + 26112);     // 8192 B

    const int t = threadIdx.x;
    const int lane = t & 63;
    const int w = t >> 6;
    const int qw = lane >> 4;
    const int ql = lane & 15;
    const int qwg = t >> 4;
    const int b = blockIdx.x;
    const float epsval = 1.0f + *eps_ptr;

    if (t < 256) {
        if (t < NS) {
            rcnt[t] = cnt[(size_t)t * NB + b];
            rsoff[t] = lofs[(size_t)t * NB + b];
        } else { rcnt[t] = 0; rsoff[t] = 0; }
    }
    __syncthreads();
    {
        int v = (t < 256) ? rcnt[t] : 0;
        int si = v;
#pragma unroll
        for (int d = 1; d < 64; d <<= 1) {
            int u = __shfl_up(si, d);
            if (lane >= d) si += u;
        }
        if (t < 256 && lane == 63) wtot[w] = si;
        __syncthreads();
        if (t == 0) {
            int a = 0;
#pragma unroll
            for (int k = 0; k < 4; ++k) { int x = wtot[k]; wtot[k] = a; a += x; }
        }
        __syncthreads();
        if (t < 256) rpre[t] = wtot[w] + si - v;
        if (t == 255) etot = wtot[3] + si;
        __syncthreads();
    }
    const int e_b = etot;

    float a[4][8];
#pragma unroll
    for (int i = 0; i < 4; ++i)
#pragma unroll
        for (int k = 0; k < 8; ++k) a[i][k] = 0.f;

    for (int p0 = 0; p0 < e_b; p0 += CAP) {
        const int cnp = min(CAP, e_b - p0);
        for (int s = qwg; s < NS; s += 64) {
            int rc = rcnt[s];
            if (rc == 0) continue;
            int rp = rpre[s];
            if (rp >= p0 + cnp || rp + rc <= p0) continue;
            int base = s * SCHUNK + rsoff[s];
            for (int o = ql; o < rc; o += 16) {
                int g = rp + o;
                if (g >= p0 && g < p0 + cnp) sbufA[g - p0] = packed[base + o];
            }
        }
        if (t < 512) bins[t] = 0;
        __syncthreads();
        for (int i = t; i < cnp; i += 1024) {
            unsigned e = sbufA[i];
            int key = (int)((((e & 0xffffu) >> CSH) << 6) | ((e >> 16) & 63u));
            atomicAdd(&bins[key], 1);
        }
        __syncthreads();
        {
            int v = (t < 512) ? bins[t] : 0;
            int si = v;
#pragma unroll
            for (int d = 1; d < 64; d <<= 1) {
                int u = __shfl_up(si, d);
                if (lane >= d) si += u;
            }
            if (t < 512 && lane == 63) wtot[w] = si;
            __syncthreads();
            if (t == 0) {
                int a2 = 0;
#pragma unroll
                for (int k = 0; k < 8; ++k) { int x = wtot[k]; wtot[k] = a2; a2 += x; }
            }
            __syncthreads();
            if (t < 512) {
                int excl = wtot[w] + si - v;
                cofs[t] = excl; ccur[t] = excl;
                if (t == 511) cofs[512] = excl + v;
            }
        }
        __syncthreads();
        for (int i = t; i < cnp; i += 1024) {
            unsigned e = sbufA[i];
            int key = (int)((((e & 0xffffu) >> CSH) << 6) | ((e >> 16) & 63u));
            int pos = atomicAdd(&ccur[key], 1);
            sbufB[pos] = (ushort)(e & 0xffffu);
        }
        __syncthreads();

        // batched 4-node gather
        for (int c = 0; c < NCH; ++c) {
            const int kbase = c * 64 + w * 4;
            int jc0 = cofs[kbase + 0] + qw; const int je0 = cofs[kbase + 1];
            int jc1 = cofs[kbase + 1] + qw; const int je1 = cofs[kbase + 2];
            int jc2 = cofs[kbase + 2] + qw; const int je2 = cofs[kbase + 3];
            int jc3 = cofs[kbase + 3] + qw; const int je3 = cofs[kbase + 4];
            while ((jc0 < je0) | (jc1 < je1) | (jc2 < je2) | (jc3 < je3)) {
                const bool a0 = jc0 < je0, a1 = jc1 < je1,
                           a2 = jc2 < je2, a3 = jc3 < je3;
                int s0 = a0 ? (int)sbufB[jc0] : 0;
                int s1 = a1 ? (int)sbufB[jc1] : 0;
                int s2 = a2 ? (int)sbufB[jc2] : 0;
                int s3 = a3 ? (int)sbufB[jc3] : 0;
                uint4 u0 = ((const uint4*)(hb + (size_t)s0 * DD))[ql];
                uint4 u1 = ((const uint4*)(hb + (size_t)s1 * DD))[ql];
                uint4 u2 = ((const uint4*)(hb + (size_t)s2 * DD))[ql];
                uint4 u3 = ((const uint4*)(hb + (size_t)s3 * DD))[ql];
                const float m0 = a0 ? 1.f : 0.f, m1 = a1 ? 1.f : 0.f;
                const float m2 = a2 ? 1.f : 0.f, m3 = a3 ? 1.f : 0.f;
                a[0][0] = fmaf(m0, lo16(u0.x), a[0][0]);
                a[0][1] = fmaf(m0, hi16(u0.x), a[0][1]);
                a[0][2] = fmaf(m0, lo16(u0.y), a[0][2]);
                a[0][3] = fmaf(m0, hi16(u0.y), a[0][3]);
                a[0][4] = fmaf(m0, lo16(u0.z), a[0][4]);
                a[0][5] = fmaf(m0, hi16(u0.z), a[0][5]);
                a[0][6] = fmaf(m0, lo16(u0.w), a[0][6]);
                a[0][7] = fmaf(m0, hi16(u0.w), a[0][7]);
                a[1][0] = fmaf(m1, lo16(u1.x), a[1][0]);
                a[1][1] = fmaf(m1, hi16(u1.x), a[1][1]);
                a[1][2] = fmaf(m1, lo16(u1.y), a[1][2]);
                a[1][3] = fmaf(m1, hi16(u1.y), a[1][3]);
                a[1][4] = fmaf(m1, lo16(u1.z), a[1][4]);
                a[1][5] = fmaf(m1, hi16(u1.z), a[1][5]);
                a[1][6] = fmaf(m1, lo16(u1.w), a[1][6]);
                a[1][7] = fmaf(m1, hi16(u1.w), a[1][7]);
                a[2][0] = fmaf(m2, lo16(u2.x), a[2][0]);
                a[2][1] = fmaf(m2, hi16(u2.x), a[2][1]);
                a[2][2] = fmaf(m2, lo16(u2.y), a[2][2]);
                a[2][3] = fmaf(m2, hi16(u2.y), a[2][3]);
                a[2][4] = fmaf(m2, lo16(u2.z), a[2][4]);
                a[2][5] = fmaf(m2, hi16(u2.z), a[2][5]);
                a[2][6] = fmaf(m2, lo16(u2.w), a[2][6]);
                a[2][7] = fmaf(m2, hi16(u2.w), a[2][7]);
                a[3][0] = fmaf(m3, lo16(u3.x), a[3][0]);
                a[3][1] = fmaf(m3, hi16(u3.x), a[3][1]);
                a[3][2] = fmaf(m3, lo16(u3.y), a[3][2]);
                a[3][3] = fmaf(m3, hi16(u3.y), a[3][3]);
                a[3][4] = fmaf(m3, lo16(u3.z), a[3][4]);
                a[3][5] = fmaf(m3, hi16(u3.z), a[3][5]);
                a[3][6] = fmaf(m3, lo16(u3.w), a[3][6]);
                a[3][7] = fmaf(m3, hi16(u3.w), a[3][7]);
                jc0 += 4; jc1 += 4; jc2 += 4; jc3 += 4;
            }
        }
        __syncthreads();
    }

#pragma unroll
    for (int i = 0; i < 4; ++i)
#pragma unroll
        for (int k = 0; k < 8; ++k) {
            a[i][k] += __shfl_down(a[i][k], 32);
            a[i][k] += __shfl_down(a[i][k], 16);
        }

    // ---- Phase B: GEMM1 on this block's 64-row tile ----
    ushort (*As)[136] = (ushort(*)[136])smem;             // 17408 B
    ushort (*Ws)[136] = (ushort(*)[136])(smem + 17408);   // 34816 B
    const int r0 = b << BSH;

    if (qw == 0) {
#pragma unroll
        for (int i = 0; i < 4; ++i) {
            int ulocal = w * 4 + i;
            int u = r0 + ulocal;
            uint4 st = make_uint4(0, 0, 0, 0);
            if (u < n) {
                uint4 hv = ((const uint4*)(hb + (size_t)u * DD))[ql];
                unsigned p0w = (unsigned)f2b(epsval * lo16(hv.x) + a[i][0])
                             | ((unsigned)f2b(epsval * hi16(hv.x) + a[i][1]) << 16);
                unsigned p1w = (unsigned)f2b(epsval * lo16(hv.y) + a[i][2])
                             | ((unsigned)f2b(epsval * hi16(hv.y) + a[i][3]) << 16);
                unsigned p2w = (unsigned)f2b(epsval * lo16(hv.z) + a[i][4])
                             | ((unsigned)f2b(epsval * hi16(hv.z) + a[i][5]) << 16);
                unsigned p3w = (unsigned)f2b(epsval * lo16(hv.w) + a[i][6])
                             | ((unsigned)f2b(epsval * hi16(hv.w) + a[i][7]) << 16);
                st = make_uint4(p0w, p1w, p2w, p3w);
            }
            *(uint4*)&As[ulocal][ql * 8] = st;
        }
    }
#pragma unroll
    for (int jj = 0; jj < 2; ++jj) {
        int f = jj * 1024 + t;
        int r = f >> 4, c8 = f & 15;
        *(uint4*)&Ws[r][c8 * 8] = ((const uint4*)wt)[f];
    }
    __syncthreads();

    const int m = w & 3;
    const int npair = w >> 2;
    short8 afr[4];
    const ushort* arow = &As[m * 16 + ql][0];
#pragma unroll
    for (int k = 0; k < 4; ++k)
        afr[k] = *(const short8*)(arow + k * 32 + qw * 8);
#pragma unroll
    for (int nn = 0; nn < 2; ++nn) {
        int nt = npair * 2 + nn;
        const ushort* brow = &Ws[nt * 16 + ql][0];
        float4v acc = (float4v)(0.f);
#pragma unroll
        for (int k = 0; k < 4; ++k) {
            short8 bfr = *(const short8*)(brow + k * 32 + qw * 8);
            acc = __builtin_amdgcn_mfma_f32_16x16x32_bf16(afr[k], bfr, acc, 0, 0, 0);
        }
        float bv = bias[nt * 16 + ql];
#pragma unroll
        for (int r = 0; r < 4; ++r) {
            int row = r0 + m * 16 + qw * 4 + r;
            if (row < n) {
                float o = fmaxf(acc[r] + bv, 0.f);
                z1b[(size_t)row * DD + nt * 16 + ql] = f2b(o);
            }
        }
    }
}

// ---------- K3: MFMA GEMM2 -> z2 (bf16) + BN stats (fp32-exact) ----------
__global__ __launch_bounds__(256) void mgemm2_kernel(
        const ushort* __restrict__ Ab, const ushort* __restrict__ wt,
        const float* __restrict__ bias, ushort* __restrict__ z2b,
        float* __restrict__ stats, int n) {
    __shared__ ushort As[64][136];
    __shared__ ushort Ws[128][136];
    __shared__ float Ssum[128];
    __shared__ float Ssq[128];

    const int t = threadIdx.x;
    const int lane = t & 63;
    const int w = t >> 6;
    const int quad = lane >> 4;
    const int l16 = lane & 15;
    const int row0 = blockIdx.x * 64;

    if (t < 128) { Ssum[t] = 0.f; Ssq[t] = 0.f; }

#pragma unroll
    for (int jj = 0; jj < 8; ++jj) {
        int f = jj * 256 + t;
        int r = f >> 4, c8 = f & 15;
        *(uint4*)&Ws[r][c8 * 8] = ((const uint4*)wt)[f];
    }
#pragma unroll
    for (int jj = 0; jj < 4; ++jj) {
        int p = jj * 256 + t;
        int r = p >> 4;
        int c8 = p & 15;
        int row = row0 + r;
        uint4 v = make_uint4(0, 0, 0, 0);
        if (row < n)
            v = *((const uint4*)(Ab + (size_t)row * DD) + c8);
        *(uint4*)&As[r][c8 * 8] = v;
    }
    __syncthreads();

    short8 afr[4];
    const ushort* arow = &As[w * 16 + l16][0];
#pragma unroll
    for (int k = 0; k < 4; ++k)
        afr[k] = *(const short8*)(arow + k * 32 + quad * 8);

    float4v acc[8];
#pragma unroll
    for (int i = 0; i < 8; ++i) acc[i] = (float4v)(0.f);

#pragma unroll
    for (int nt = 0; nt < 8; ++nt) {
        const ushort* brow = &Ws[nt * 16 + l16][0];
#pragma unroll
        for (int k = 0; k < 4; ++k) {
            short8 bfr = *(const short8*)(brow + k * 32 + quad * 8);
            acc[nt] = __builtin_amdgcn_mfma_f32_16x16x32_bf16(afr[k], bfr, acc[nt], 0, 0, 0);
        }
    }

#pragma unroll
    for (int nt = 0; nt < 8; ++nt) {
        float bv = bias[nt * 16 + l16];
        float s = 0.f, q = 0.f;
#pragma unroll
        for (int r = 0; r < 4; ++r) {
            int row = row0 + w * 16 + quad * 4 + r;
            if (row < n) {
                float o = acc[nt][r] + bv;
                z2b[(size_t)row * DD + nt * 16 + l16] = f2b(o);
                s += o;
                q += o * o;
            }
        }
        atomicAdd(&Ssum[nt * 16 + l16], s);
        atomicAdd(&Ssq[nt * 16 + l16], q);
    }
    __syncthreads();
    if (t < 128) {
        atomicAdd(&stats[t], Ssum[t]);
        atomicAdd(&stats[128 + t], Ssq[t]);
    }
}

// ---------- K4: BN finalize (in-block) + leaky relu + residual ----------
__global__ __launch_bounds__(256) void applybn_kernel(
        const float* __restrict__ h, const ushort* __restrict__ z2b,
        const float* __restrict__ stats, const float* __restrict__ gamma,
        const float* __restrict__ beta, float* __restrict__ out,
        int n, int total4) {
    __shared__ float sc[128];
    __shared__ float sh[128];
    const int t = threadIdx.x;
    if (t < 128) {
        float inv_n = 1.0f / (float)n;
        float mean = stats[t] * inv_n;
        float var = stats[128 + t] * inv_n - mean * mean;
        float s = gamma[t] * rsqrtf(var + BN_EPS);
        sc[t] = s;
        sh[t] = beta[t] - mean * s;
    }
    __syncthreads();
    for (int i = blockIdx.x * 256 + t; i < total4; i += gridDim.x * 256) {
        int c4 = i & 31;
        float4 scv = ((const float4*)sc)[c4];
        float4 shv = ((const float4*)sh)[c4];
        uint2 zb = ((const uint2*)z2b)[i];
        float4 hh = ((const float4*)h)[i];
        float4 o;
        float v;
        v = fmaf(lo16(zb.x), scv.x, shv.x); o.x = hh.x + (v >= 0.f ? v : SLOPE * v);
        v = fmaf(hi16(zb.x), scv.y, shv.y); o.y = hh.y + (v >= 0.f ? v : SLOPE * v);
        v = fmaf(lo16(zb.y), scv.z, shv.z); o.z = hh.z + (v >= 0.f ? v : SLOPE * v);
        v = fmaf(hi16(zb.y), scv.w, shv.w); o.w = hh.w + (v >= 0.f ? v : SLOPE * v);
        ((float4*)out)[i] = o;
    }
}

extern "C" void kernel_launch(void* const* d_in, const int* in_sizes, int n_in,
                              void* d_out, int out_size, void* d_ws, size_t ws_size,
                              hipStream_t stream) {
    const float* h     = (const float*)d_in[0];
    const int*   src   = (const int*)d_in[1];
    const int*   dst   = (const int*)d_in[2];
    const float* eps   = (const float*)d_in[3];
    const float* W1    = (const float*)d_in[4];
    const float* b1    = (const float*)d_in[5];
    const float* W2    = (const float*)d_in[6];
    const float* b2    = (const float*)d_in[7];
    const float* gamma = (const float*)d_in[8];
    const float* beta  = (const float*)d_in[9];
    float* out = (float*)d_out;

    const int n = in_sizes[0] / DD;   // 50000
    const int E = in_sizes[1];        // 1600000
    const int NB = (n + BROWS - 1) / BROWS;    // 782
    const int NS = (E + SCHUNK - 1) / SCHUNK;  // 196
    const int total4 = n * DD / 4;

    // workspace layout: z1b | z2b | hb | packed | cnt | lofs | stats | wt1 | wt2
    ushort* z1b      = (ushort*)d_ws;
    ushort* z2b      = z1b + (size_t)n * DD;
    ushort* hb       = z2b + (size_t)n * DD;
    unsigned* packed = (unsigned*)(hb + (size_t)n * DD);
    int* cnt         = (int*)(packed + (size_t)NS * SCHUNK);
    int* lofs        = cnt + (size_t)NS * NB;
    float* stats     = (float*)(lofs + (size_t)NS * NB);
    ushort* wt1      = (ushort*)(stats + 256);
    ushort* wt2      = wt1 + DD * DD;

    // K1: role-split — chunk sort + prep (h->bf16, W->bf16^T, stats zero)
    scatb6_kernel<<<NS + PREPB, 1024, 0, stream>>>(
        h, hb, W1, W2, wt1, wt2, src, dst, cnt, lofs, packed, stats,
        NS, total4, E, NB);
    // K2: fused gather + GEMM1 -> z1b (2 blocks/CU, spill accepted; batched gather)
    aggemm_kernel<<<NB, 1024, 0, stream>>>(hb, cnt, lofs, packed, eps, wt1, b1,
                                           z1b, n, NB, NS);
    // K3: GEMM2 -> z2 (bf16) + BN stats
    mgemm2_kernel<<<(n + 63) / 64, 256, 0, stream>>>(z1b, wt2, b2, z2b, stats, n);
    // K4: BN finalize + leaky relu + residual -> out
    applybn_kernel<<<1024, 256, 0, stream>>>(h, z2b, stats, gamma, beta, out,
                                             n, total4);
}

// Round 15
// 243.940 us; speedup vs baseline: 1.1651x; 1.1651x over previous
//
#include <hip/hip_runtime.h>
#include <cstddef>

#define DD 128
#define BN_EPS 1e-5f
#define SLOPE 0.01f
#define BSH 6              // 64 dst rows per bucket
#define BROWS 64
#define CAP 4096           // aggemm per-window edge capacity in LDS
#define SCHUNK 8192        // scatb per-block edge chunk
#define CSH 13             // src-chunk shift: 8192 rows = 2 MB bf16, L2-resident
#define NCH 7              // ceil(50000/8192)
#define PREPB 200          // dedicated prep blocks in K1

typedef __attribute__((ext_vector_type(8))) short short8;
typedef __attribute__((ext_vector_type(4))) float float4v;

__device__ __forceinline__ unsigned short f2b(float x) {
    unsigned b = __float_as_uint(x);
    b += 0x7fffu + ((b >> 16) & 1u);   // round-to-nearest-even
    return (unsigned short)(b >> 16);
}
__device__ __forceinline__ float lo16(unsigned x) { return __uint_as_float(x << 16); }
__device__ __forceinline__ float hi16(unsigned x) { return __uint_as_float(x & 0xffff0000u); }

// ---------- K1: role-split — sort blocks [0,NS) + prep blocks [NS,NS+PREPB) ----------
__global__ __launch_bounds__(1024) void scatb6_kernel(
        const float* __restrict__ h, ushort* __restrict__ hb,
        const float* __restrict__ W1, const float* __restrict__ W2,
        ushort* __restrict__ wt1, ushort* __restrict__ wt2,
        const int* __restrict__ src, const int* __restrict__ dst,
        int* __restrict__ cnt, int* __restrict__ lofs,
        unsigned* __restrict__ packed, float* __restrict__ stats,
        int NS, int total4, int E, int NB) {
    __shared__ int bins[1024];
    __shared__ int lcur[1024];
    __shared__ int wtot[16];
    __shared__ unsigned sbuf[SCHUNK];

    const int t = threadIdx.x;
    const int blk = blockIdx.x;

    if (blk >= NS) {
        // ---- prep role ----
        const int pb = blk - NS;
        const int gid = pb * 1024 + t;
        const int gstride = PREPB * 1024;
        if (pb == 0 && t < 256) stats[t] = 0.f;
        for (int i = gid; i < total4; i += gstride) {
            float4 v = ((const float4*)h)[i];
            ushort4 o;
            o.x = f2b(v.x); o.y = f2b(v.y); o.z = f2b(v.z); o.w = f2b(v.w);
            ((ushort4*)hb)[i] = o;
        }
        for (int i = gid; i < 2 * DD * DD; i += gstride) {
            int wsel = i >> 14;
            int r = i & 16383;
            int c = r >> 7, k = r & 127;
            const float* Wsrc = wsel ? W2 : W1;
            ushort* Wdst = wsel ? wt2 : wt1;
            Wdst[c * DD + k] = f2b(Wsrc[k * DD + c]);
        }
        return;
    }

    // ---- sort role ----
    const int lane = t & 63;
    const int w = t >> 6;
    const int s = blk;
    const int cs = s * SCHUNK;
    const int cn = min(SCHUNK, E - cs);

    bins[t] = 0;
    __syncthreads();
    for (int i = t; i < cn; i += 1024) atomicAdd(&bins[dst[cs + i] >> BSH], 1);
    __syncthreads();
    int v = bins[t];
    int si = v;
#pragma unroll
    for (int d = 1; d < 64; d <<= 1) {
        int u = __shfl_up(si, d);
        if (lane >= d) si += u;
    }
    if (lane == 63) wtot[w] = si;
    __syncthreads();
    if (t == 0) {
        int a = 0;
#pragma unroll
        for (int k = 0; k < 16; ++k) { int x = wtot[k]; wtot[k] = a; a += x; }
    }
    __syncthreads();
    int excl = wtot[w] + si - v;
    lcur[t] = excl;
    if (t < NB) {
        cnt[(size_t)s * NB + t] = v;
        lofs[(size_t)s * NB + t] = excl;
    }
    __syncthreads();
    for (int i = t; i < cn; i += 1024) {
        int d = dst[cs + i];
        int b = d >> BSH;
        int pos = atomicAdd(&lcur[b], 1);
        sbuf[pos] = ((unsigned)(d & (BROWS - 1)) << 16) | (unsigned)src[cs + i];
    }
    __syncthreads();
    for (int i = t; i < cn; i += 1024) packed[cs + i] = sbuf[i];
}

// ---------- K2: fused gather + GEMM1 (R13 gather core — do not modify) ----------
// __launch_bounds__(1024, 8): 2 blocks/CU, accumulators partially spill
// (~50 MB scratch). A/B history: R12 spill-free 1 blk/CU = 124us; R13 this
// form = 93us; R14 batched-4 gather = 136us (extra live state -> 112 MB
// spill). The VGPR-64 budget is a knife-edge: ANY added live state in the
// gather loop converts to scratch traffic. Keep the simple sequential loop.
__global__ __launch_bounds__(1024, 8) void aggemm_kernel(
        const ushort* __restrict__ hb, const int* __restrict__ cnt,
        const int* __restrict__ lofs, const unsigned* __restrict__ packed,
        const float* __restrict__ eps_ptr, const ushort* __restrict__ wt,
        const float* __restrict__ bias, ushort* __restrict__ z1b,
        int n, int NB, int NS) {
    __shared__ __align__(16) char smem[52224];
    __shared__ int wtot[16];
    __shared__ int etot;

    int* rcnt  = (int*)smem;                       // 256
    int* rsoff = rcnt + 256;                       // 256
    int* rpre  = rsoff + 256;                      // 256
    int* bins  = rpre + 256;                       // 512
    int* cofs  = bins + 512;                       // 513
    int* ccur  = cofs + 513;                       // 512
    unsigned* sbufA = (unsigned*)(smem + 9728);    // 16384 B
    ushort*  sbufB  = (ushort*)(smem + 26112);     // 8192 B

    const int t = threadIdx.x;
    const int lane = t & 63;
    const int w = t >> 6;
    const int qw = lane >> 4;
    const int ql = lane & 15;
    const int qwg = t >> 4;
    const int b = blockIdx.x;
    const float epsval = 1.0f + *eps_ptr;

    if (t < 256) {
        if (t < NS) {
            rcnt[t] = cnt[(size_t)t * NB + b];
            rsoff[t] = lofs[(size_t)t * NB + b];
        } else { rcnt[t] = 0; rsoff[t] = 0; }
    }
    __syncthreads();
    {
        int v = (t < 256) ? rcnt[t] : 0;
        int si = v;
#pragma unroll
        for (int d = 1; d < 64; d <<= 1) {
            int u = __shfl_up(si, d);
            if (lane >= d) si += u;
        }
        if (t < 256 && lane == 63) wtot[w] = si;
        __syncthreads();
        if (t == 0) {
            int a = 0;
#pragma unroll
            for (int k = 0; k < 4; ++k) { int x = wtot[k]; wtot[k] = a; a += x; }
        }
        __syncthreads();
        if (t < 256) rpre[t] = wtot[w] + si - v;
        if (t == 255) etot = wtot[3] + si;
        __syncthreads();
    }
    const int e_b = etot;

    float a[4][8];
#pragma unroll
    for (int i = 0; i < 4; ++i)
#pragma unroll
        for (int k = 0; k < 8; ++k) a[i][k] = 0.f;

    for (int p0 = 0; p0 < e_b; p0 += CAP) {
        const int cnp = min(CAP, e_b - p0);
        for (int s = qwg; s < NS; s += 64) {
            int rc = rcnt[s];
            if (rc == 0) continue;
            int rp = rpre[s];
            if (rp >= p0 + cnp || rp + rc <= p0) continue;
            int base = s * SCHUNK + rsoff[s];
            for (int o = ql; o < rc; o += 16) {
                int g = rp + o;
                if (g >= p0 && g < p0 + cnp) sbufA[g - p0] = packed[base + o];
            }
        }
        if (t < 512) bins[t] = 0;
        __syncthreads();
        for (int i = t; i < cnp; i += 1024) {
            unsigned e = sbufA[i];
            int key = (int)((((e & 0xffffu) >> CSH) << 6) | ((e >> 16) & 63u));
            atomicAdd(&bins[key], 1);
        }
        __syncthreads();
        {
            int v = (t < 512) ? bins[t] : 0;
            int si = v;
#pragma unroll
            for (int d = 1; d < 64; d <<= 1) {
                int u = __shfl_up(si, d);
                if (lane >= d) si += u;
            }
            if (t < 512 && lane == 63) wtot[w] = si;
            __syncthreads();
            if (t == 0) {
                int a2 = 0;
#pragma unroll
                for (int k = 0; k < 8; ++k) { int x = wtot[k]; wtot[k] = a2; a2 += x; }
            }
            __syncthreads();
            if (t < 512) {
                int excl = wtot[w] + si - v;
                cofs[t] = excl; ccur[t] = excl;
                if (t == 511) cofs[512] = excl + v;
            }
        }
        __syncthreads();
        for (int i = t; i < cnp; i += 1024) {
            unsigned e = sbufA[i];
            int key = (int)((((e & 0xffffu) >> CSH) << 6) | ((e >> 16) & 63u));
            int pos = atomicAdd(&ccur[key], 1);
            sbufB[pos] = (ushort)(e & 0xffffu);
        }
        __syncthreads();

        for (int c = 0; c < NCH; ++c) {
            const int kbase = c * 64 + w * 4;
#pragma unroll
            for (int i = 0; i < 4; ++i) {
                const int jb = cofs[kbase + i];
                const int je = cofs[kbase + i + 1];
                for (int j = jb + qw; j < je; j += 4) {
                    int sV = sbufB[j];
                    uint4 u = ((const uint4*)(hb + (size_t)sV * DD))[ql];
                    a[i][0] += lo16(u.x); a[i][1] += hi16(u.x);
                    a[i][2] += lo16(u.y); a[i][3] += hi16(u.y);
                    a[i][4] += lo16(u.z); a[i][5] += hi16(u.z);
                    a[i][6] += lo16(u.w); a[i][7] += hi16(u.w);
                }
            }
        }
        __syncthreads();
    }

#pragma unroll
    for (int i = 0; i < 4; ++i)
#pragma unroll
        for (int k = 0; k < 8; ++k) {
            a[i][k] += __shfl_down(a[i][k], 32);
            a[i][k] += __shfl_down(a[i][k], 16);
        }

    // ---- Phase B: GEMM1 on this block's 64-row tile ----
    ushort (*As)[136] = (ushort(*)[136])smem;             // 17408 B
    ushort (*Ws)[136] = (ushort(*)[136])(smem + 17408);   // 34816 B
    const int r0 = b << BSH;

    if (qw == 0) {
#pragma unroll
        for (int i = 0; i < 4; ++i) {
            int ulocal = w * 4 + i;
            int u = r0 + ulocal;
            uint4 st = make_uint4(0, 0, 0, 0);
            if (u < n) {
                uint4 hv = ((const uint4*)(hb + (size_t)u * DD))[ql];
                unsigned p0w = (unsigned)f2b(epsval * lo16(hv.x) + a[i][0])
                             | ((unsigned)f2b(epsval * hi16(hv.x) + a[i][1]) << 16);
                unsigned p1w = (unsigned)f2b(epsval * lo16(hv.y) + a[i][2])
                             | ((unsigned)f2b(epsval * hi16(hv.y) + a[i][3]) << 16);
                unsigned p2w = (unsigned)f2b(epsval * lo16(hv.z) + a[i][4])
                             | ((unsigned)f2b(epsval * hi16(hv.z) + a[i][5]) << 16);
                unsigned p3w = (unsigned)f2b(epsval * lo16(hv.w) + a[i][6])
                             | ((unsigned)f2b(epsval * hi16(hv.w) + a[i][7]) << 16);
                st = make_uint4(p0w, p1w, p2w, p3w);
            }
            *(uint4*)&As[ulocal][ql * 8] = st;
        }
    }
#pragma unroll
    for (int jj = 0; jj < 2; ++jj) {
        int f = jj * 1024 + t;
        int r = f >> 4, c8 = f & 15;
        *(uint4*)&Ws[r][c8 * 8] = ((const uint4*)wt)[f];
    }
    __syncthreads();

    const int m = w & 3;
    const int npair = w >> 2;
    short8 afr[4];
    const ushort* arow = &As[m * 16 + ql][0];
#pragma unroll
    for (int k = 0; k < 4; ++k)
        afr[k] = *(const short8*)(arow + k * 32 + qw * 8);
#pragma unroll
    for (int nn = 0; nn < 2; ++nn) {
        int nt = npair * 2 + nn;
        const ushort* brow = &Ws[nt * 16 + ql][0];
        float4v acc = (float4v)(0.f);
#pragma unroll
        for (int k = 0; k < 4; ++k) {
            short8 bfr = *(const short8*)(brow + k * 32 + qw * 8);
            acc = __builtin_amdgcn_mfma_f32_16x16x32_bf16(afr[k], bfr, acc, 0, 0, 0);
        }
        float bv = bias[nt * 16 + ql];
#pragma unroll
        for (int r = 0; r < 4; ++r) {
            int row = r0 + m * 16 + qw * 4 + r;
            if (row < n) {
                float o = fmaxf(acc[r] + bv, 0.f);
                z1b[(size_t)row * DD + nt * 16 + ql] = f2b(o);
            }
        }
    }
}

// ---------- K3: MFMA GEMM2 -> z2 (bf16) + BN stats (fp32-exact) ----------
__global__ __launch_bounds__(256) void mgemm2_kernel(
        const ushort* __restrict__ Ab, const ushort* __restrict__ wt,
        const float* __restrict__ bias, ushort* __restrict__ z2b,
        float* __restrict__ stats, int n) {
    __shared__ ushort As[64][136];
    __shared__ ushort Ws[128][136];
    __shared__ float Ssum[128];
    __shared__ float Ssq[128];

    const int t = threadIdx.x;
    const int lane = t & 63;
    const int w = t >> 6;
    const int quad = lane >> 4;
    const int l16 = lane & 15;
    const int row0 = blockIdx.x * 64;

    if (t < 128) { Ssum[t] = 0.f; Ssq[t] = 0.f; }

#pragma unroll
    for (int jj = 0; jj < 8; ++jj) {
        int f = jj * 256 + t;
        int r = f >> 4, c8 = f & 15;
        *(uint4*)&Ws[r][c8 * 8] = ((const uint4*)wt)[f];
    }
#pragma unroll
    for (int jj = 0; jj < 4; ++jj) {
        int p = jj * 256 + t;
        int r = p >> 4;
        int c8 = p & 15;
        int row = row0 + r;
        uint4 v = make_uint4(0, 0, 0, 0);
        if (row < n)
            v = *((const uint4*)(Ab + (size_t)row * DD) + c8);
        *(uint4*)&As[r][c8 * 8] = v;
    }
    __syncthreads();

    short8 afr[4];
    const ushort* arow = &As[w * 16 + l16][0];
#pragma unroll
    for (int k = 0; k < 4; ++k)
        afr[k] = *(const short8*)(arow + k * 32 + quad * 8);

    float4v acc[8];
#pragma unroll
    for (int i = 0; i < 8; ++i) acc[i] = (float4v)(0.f);

#pragma unroll
    for (int nt = 0; nt < 8; ++nt) {
        const ushort* brow = &Ws[nt * 16 + l16][0];
#pragma unroll
        for (int k = 0; k < 4; ++k) {
            short8 bfr = *(const short8*)(brow + k * 32 + quad * 8);
            acc[nt] = __builtin_amdgcn_mfma_f32_16x16x32_bf16(afr[k], bfr, acc[nt], 0, 0, 0);
        }
    }

#pragma unroll
    for (int nt = 0; nt < 8; ++nt) {
        float bv = bias[nt * 16 + l16];
        float s = 0.f, q = 0.f;
#pragma unroll
        for (int r = 0; r < 4; ++r) {
            int row = row0 + w * 16 + quad * 4 + r;
            if (row < n) {
                float o = acc[nt][r] + bv;
                z2b[(size_t)row * DD + nt * 16 + l16] = f2b(o);
                s += o;
                q += o * o;
            }
        }
        atomicAdd(&Ssum[nt * 16 + l16], s);
        atomicAdd(&Ssq[nt * 16 + l16], q);
    }
    __syncthreads();
    if (t < 128) {
        atomicAdd(&stats[t], Ssum[t]);
        atomicAdd(&stats[128 + t], Ssq[t]);
    }
}

// ---------- K4: BN finalize (in-block) + leaky relu + residual ----------
__global__ __launch_bounds__(256) void applybn_kernel(
        const float* __restrict__ h, const ushort* __restrict__ z2b,
        const float* __restrict__ stats, const float* __restrict__ gamma,
        const float* __restrict__ beta, float* __restrict__ out,
        int n, int total4) {
    __shared__ float sc[128];
    __shared__ float sh[128];
    const int t = threadIdx.x;
    if (t < 128) {
        float inv_n = 1.0f / (float)n;
        float mean = stats[t] * inv_n;
        float var = stats[128 + t] * inv_n - mean * mean;
        float s = gamma[t] * rsqrtf(var + BN_EPS);
        sc[t] = s;
        sh[t] = beta[t] - mean * s;
    }
    __syncthreads();
    for (int i = blockIdx.x * 256 + t; i < total4; i += gridDim.x * 256) {
        int c4 = i & 31;
        float4 scv = ((const float4*)sc)[c4];
        float4 shv = ((const float4*)sh)[c4];
        uint2 zb = ((const uint2*)z2b)[i];
        float4 hh = ((const float4*)h)[i];
        float4 o;
        float v;
        v = fmaf(lo16(zb.x), scv.x, shv.x); o.x = hh.x + (v >= 0.f ? v : SLOPE * v);
        v = fmaf(hi16(zb.x), scv.y, shv.y); o.y = hh.y + (v >= 0.f ? v : SLOPE * v);
        v = fmaf(lo16(zb.y), scv.z, shv.z); o.z = hh.z + (v >= 0.f ? v : SLOPE * v);
        v = fmaf(hi16(zb.y), scv.w, shv.w); o.w = hh.w + (v >= 0.f ? v : SLOPE * v);
        ((float4*)out)[i] = o;
    }
}

extern "C" void kernel_launch(void* const* d_in, const int* in_sizes, int n_in,
                              void* d_out, int out_size, void* d_ws, size_t ws_size,
                              hipStream_t stream) {
    const float* h     = (const float*)d_in[0];
    const int*   src   = (const int*)d_in[1];
    const int*   dst   = (const int*)d_in[2];
    const float* eps   = (const float*)d_in[3];
    const float* W1    = (const float*)d_in[4];
    const float* b1    = (const float*)d_in[5];
    const float* W2    = (const float*)d_in[6];
    const float* b2    = (const float*)d_in[7];
    const float* gamma = (const float*)d_in[8];
    const float* beta  = (const float*)d_in[9];
    float* out = (float*)d_out;

    const int n = in_sizes[0] / DD;   // 50000
    const int E = in_sizes[1];        // 1600000
    const int NB = (n + BROWS - 1) / BROWS;    // 782
    const int NS = (E + SCHUNK - 1) / SCHUNK;  // 196
    const int total4 = n * DD / 4;

    // workspace layout: z1b | z2b | hb | packed | cnt | lofs | stats | wt1 | wt2
    ushort* z1b      = (ushort*)d_ws;
    ushort* z2b      = z1b + (size_t)n * DD;
    ushort* hb       = z2b + (size_t)n * DD;
    unsigned* packed = (unsigned*)(hb + (size_t)n * DD);
    int* cnt         = (int*)(packed + (size_t)NS * SCHUNK);
    int* lofs        = cnt + (size_t)NS * NB;
    float* stats     = (float*)(lofs + (size_t)NS * NB);
    ushort* wt1      = (ushort*)(stats + 256);
    ushort* wt2      = wt1 + DD * DD;

    // K1: role-split — chunk sort + prep (h->bf16, W->bf16^T, stats zero)
    scatb6_kernel<<<NS + PREPB, 1024, 0, stream>>>(
        h, hb, W1, W2, wt1, wt2, src, dst, cnt, lofs, packed, stats,
        NS, total4, E, NB);
    // K2: fused gather + GEMM1 -> z1b (R13 gather core)
    aggemm_kernel<<<NB, 1024, 0, stream>>>(hb, cnt, lofs, packed, eps, wt1, b1,
                                           z1b, n, NB, NS);
    // K3: GEMM2 -> z2 (bf16) + BN stats
    mgemm2_kernel<<<(n + 63) / 64, 256, 0, stream>>>(z1b, wt2, b2, z2b, stats, n);
    // K4: BN finalize + leaky relu + residual -> out
    applybn_kernel<<<1024, 256, 0, stream>>>(h, z2b, stats, gamma, beta, out,
                                             n, total4);
}